// Round 24
// baseline (523.465 us; speedup 1.0000x reference)
//
#include <hip/hip_runtime.h>
#include <hip/hip_bf16.h>

#define DEV __device__ __forceinline__

typedef __bf16 bf16x8 __attribute__((ext_vector_type(8)));
typedef float f32x4 __attribute__((ext_vector_type(4)));

DEV f32x4 mfma16(bf16x8 a, bf16x8 b, f32x4 c) {
  return __builtin_amdgcn_mfma_f32_16x16x32_bf16(a, b, c, 0, 0, 0);
}

DEV ushort f2bf(float f) {
  union { __hip_bfloat16 h; ushort u; } cv;
  cv.h = __float2bfloat16(f);
  return cv.u;
}
DEV float bf2f(ushort u) {
  union { float f; unsigned v; } cv; cv.v = ((unsigned)u) << 16; return cv.f;
}

// bare v_exp_f32 (2^x): no mul, no libm guards (r20/r21 lesson)
DEV float fexp2(float x) { return __builtin_amdgcn_exp2f(x); }

// async global->LDS, 16B/lane; LDS dest linear in lane
#define GLD16(gp, lp)                                                              \
  __builtin_amdgcn_global_load_lds(                                                \
      (const __attribute__((address_space(1))) unsigned int*)(gp),                 \
      (__attribute__((address_space(3))) unsigned int*)(lp), 16, 0, 0)

// ---------------- constants ----------------
// B=4 H=8 S=2048 D=256; BH=32; M=B*S=8192
// Q pre-scaled by log2(e)/16 so attention exp is a single v_exp_f32.
// K global layout: [bh][t][256] bf16, pre-swizzled: chunk(e>>3) ^= (t&7)
// V global layout: [bh][ttile=t/32][256 e][32 t] bf16 tiles, scaled 1/l_t (vscale)
// lp: [32 partials][32 bh][2048 t] fp32
// r23 status: 320.4us (p1 134 @46% MfmaUtil, p0 ~86, qkv ~47, out ~25).
// r24: (a) p1 3-buffer Ks ring + counted vmcnt(8) + raw s_barrier (fence no
//   longer waits for same-iter DMA; LDS 68KB keeps 2/CU so r19's occupancy
//   penalty doesn't apply); (b) qkv BK 64->128 (2 K-iters, same k-order).

// ---------------- kernel A: fp32 -> bf16 conversion ----------------
__global__ __launch_bounds__(256) void convert_all(
    const float* __restrict__ x, const float* __restrict__ wq,
    const float* __restrict__ wk, const float* __restrict__ wv,
    const float* __restrict__ wo, ushort* __restrict__ dst)
{
  size_t i = ((size_t)blockIdx.x * 256 + threadIdx.x) * 4;
  const float* src; size_t off;
  if (i < (size_t)2097152) { src = x; off = i; }
  else {
    size_t j = i - 2097152;
    unsigned wsel = (unsigned)(j >> 19);
    off = j & 524287;
    src = wsel == 0 ? wq : wsel == 1 ? wk : wsel == 2 ? wv : wo;
  }
  float4 v = *(const float4*)(src + off);
  ushort4 o;
  o.x = f2bf(v.x); o.y = f2bf(v.y); o.z = f2bf(v.z); o.w = f2bf(v.w);
  *(ushort4*)(dst + i) = o;
}

// ---------------- QKV GEMM (NT), BK=128 ----------------
// A[8192,256] x {Wq|Wk|Wv}[2048,256]^T; 2 K-iters, 64 MFMA per barrier-pair.
template<int BM, int BN>
__global__ __launch_bounds__(256, 2) void gemm_qkv(
    const ushort* __restrict__ A,
    const ushort* __restrict__ W0, const ushort* __restrict__ W1, const ushort* __restrict__ W2,
    int K,
    const float* __restrict__ b0, const float* __restrict__ b1, const float* __restrict__ b2,
    ushort* __restrict__ Qo, ushort* __restrict__ Ko, ushort* __restrict__ Vo)
{
  constexpr int WM = BM / 2, WN = BN / 2, MF = WM / 16, NF = WN / 16;
  const int n0 = blockIdx.x * BN, m0 = blockIdx.y * BM;
  const int tid = threadIdx.x, lane = tid & 63;
  const int wm = (tid >> 7) & 1, wn = (tid >> 6) & 1;
  const int g = lane >> 4, r15 = lane & 15;

  __shared__ ushort As[BM * 136];   // rows of 128 k-elems, pad 136 (2-way max)
  __shared__ ushort Bs[BN * 136];

  const int p = n0 >> 11;
  const ushort* Bt = (p == 0 ? W0 : p == 1 ? W1 : W2) + (size_t)(n0 & 2047) * K;

  f32x4 acc[MF][NF];
#pragma unroll
  for (int m = 0; m < MF; m++)
#pragma unroll
    for (int n = 0; n < NF; n++) acc[m][n] = (f32x4){0.f, 0.f, 0.f, 0.f};

  for (int k0 = 0; k0 < K; k0 += 128) {
#pragma unroll
    for (int i = 0; i < 8; i++) {
      int ci = tid * 8 + i; int r = ci >> 4, c = ci & 15;
      *(uint4*)&As[r * 136 + c * 8] = *(const uint4*)&A[(size_t)(m0 + r) * K + k0 + c * 8];
      *(uint4*)&Bs[r * 136 + c * 8] = *(const uint4*)&Bt[(size_t)r * K + k0 + c * 8];
    }
    __syncthreads();
#pragma unroll
    for (int k2 = 0; k2 < 4; ++k2) {
      bf16x8 af[MF], bfr[NF];
#pragma unroll
      for (int m = 0; m < MF; m++)
        af[m] = *(const bf16x8*)&As[(wm * WM + m * 16 + r15) * 136 + k2 * 32 + g * 8];
#pragma unroll
      for (int n = 0; n < NF; n++)
        bfr[n] = *(const bf16x8*)&Bs[(wn * WN + n * 16 + r15) * 136 + k2 * 32 + g * 8];
#pragma unroll
      for (int m = 0; m < MF; m++)
#pragma unroll
        for (int n = 0; n < NF; n++) acc[m][n] = mfma16(af[m], bfr[n], acc[m][n]);
    }
    __syncthreads();
  }

  const float* bias = (p == 0 ? b0 : p == 1 ? b1 : b2);
  const float scl = (p == 0 ? 0.0625f * 1.44269504088896f : 1.0f);
#pragma unroll
  for (int m = 0; m < MF; m++)
#pragma unroll
    for (int n = 0; n < NF; n++)
#pragma unroll
      for (int r = 0; r < 4; r++) {
        int row = m0 + wm * WM + m * 16 + g * 4 + r;
        int col = n0 + wn * WN + n * 16 + r15;
        int ce = col & 2047;
        float v = (acc[m][n][r] + bias[ce]) * scl;
        int b = row >> 11, s = row & 2047, h = ce >> 8, e = ce & 255;
        int bh = b * 8 + h;
        if (p == 0) {
          Qo[((size_t)(bh * 2048 + s) << 8) + e] = f2bf(v);
        } else if (p == 1) {
          int ee = ((((e >> 3) ^ (s & 7)) & 31) << 3) | (e & 7); // T2 pre-swizzle
          Ko[((size_t)(bh * 2048 + s) << 8) + ee] = f2bf(v);
        } else {
          Vo[(((size_t)bh * 64 + (s >> 5)) << 13) + e * 32 + (s & 31)] = f2bf(v);
        }
      }
}

// ---------------- out GEMM (r13, proven) ----------------
__global__ __launch_bounds__(256, 2) void gemm_out(
    const ushort* __restrict__ A, const ushort* __restrict__ Bw,
    const float* __restrict__ bias, float* __restrict__ out)
{
  const int n0 = blockIdx.x * 64, m0 = blockIdx.y * 64;
  const int tid = threadIdx.x, lane = tid & 63;
  const int wm = (tid >> 7) & 1, wn = (tid >> 6) & 1;
  const int g = lane >> 4, r15 = lane & 15;

  __shared__ ushort As[64 * 72];
  __shared__ ushort Bs[64 * 72];

  f32x4 acc[2][2];
#pragma unroll
  for (int m = 0; m < 2; m++)
#pragma unroll
    for (int n = 0; n < 2; n++) acc[m][n] = (f32x4){0.f, 0.f, 0.f, 0.f};

  for (int k0 = 0; k0 < 2048; k0 += 64) {
#pragma unroll
    for (int i = 0; i < 2; ++i) {
      int ci = tid * 2 + i, r = ci >> 3, c = ci & 7;
      *(uint4*)&As[r * 72 + c * 8] = *(const uint4*)&A[(size_t)(m0 + r) * 2048 + k0 + c * 8];
      *(uint4*)&Bs[r * 72 + c * 8] = *(const uint4*)&Bw[(size_t)(n0 + r) * 2048 + k0 + c * 8];
    }
    __syncthreads();
    bf16x8 af[2][2], bfr[2][2];
#pragma unroll
    for (int m = 0; m < 2; ++m)
#pragma unroll
      for (int k2 = 0; k2 < 2; ++k2)
        af[m][k2] = *(const bf16x8*)&As[(wm * 32 + m * 16 + r15) * 72 + k2 * 32 + g * 8];
#pragma unroll
    for (int n = 0; n < 2; ++n)
#pragma unroll
      for (int k2 = 0; k2 < 2; ++k2)
        bfr[n][k2] = *(const bf16x8*)&Bs[(wn * 32 + n * 16 + r15) * 72 + k2 * 32 + g * 8];
#pragma unroll
    for (int k2 = 0; k2 < 2; ++k2)
#pragma unroll
      for (int m = 0; m < 2; ++m)
#pragma unroll
        for (int n = 0; n < 2; ++n)
          acc[m][n] = mfma16(af[m][k2], bfr[n][k2], acc[m][n]);
    __syncthreads();
  }

#pragma unroll
  for (int m = 0; m < 2; m++)
#pragma unroll
    for (int n = 0; n < 2; n++)
#pragma unroll
      for (int r = 0; r < 4; r++) {
        int row = m0 + wm * 32 + m * 16 + g * 4 + r;
        int col = n0 + wn * 32 + n * 16 + r15;
        out[(size_t)row * 256 + col] = acc[m][n][r] + bias[col];
      }
}

// ---------------- attention phase 0: s-tile 256, GLD dbuf, one barrier (r22, proven) ----------------
__global__ __launch_bounds__(256, 2) void attn_p0(
    const ushort* __restrict__ Qb, const ushort* __restrict__ Kb,
    float* __restrict__ lpart)
{
  const int bid = blockIdx.x;
  const int swz = (bid & 7) * 64 + (bid >> 3);   // bijective: 512 % 8 == 0
  const int bh = swz >> 4, stile = (swz >> 1) & 7, half = swz & 1;
  const int s0 = stile * 256;
  const int tid = threadIdx.x, lane = tid & 63, w = tid >> 6;
  const int g = lane >> 4, r15 = lane & 15;

  __shared__ __align__(16) ushort Ks[2][8192];   // dbuf [32 t][256 k], swizzled

  uint4 qr[4][8];
#pragma unroll
  for (int h = 0; h < 4; ++h) {
    const ushort* qrow = &Qb[((size_t)bh * 2048 + s0 + w * 64 + h * 16 + r15) * 256 + g * 8];
#pragma unroll
    for (int kk = 0; kk < 8; kk++) qr[h][kk] = *(const uint4*)&qrow[kk * 32];
  }
#pragma unroll
  for (int h = 0; h < 4; ++h)
#pragma unroll
    for (int kk = 0; kk < 8; kk++)
      asm volatile("" : "+v"(qr[h][kk].x), "+v"(qr[h][kk].y),
                        "+v"(qr[h][kk].z), "+v"(qr[h][kk].w));

  const ushort* Ktile = Kb + ((size_t)bh << 19);
  const int it0 = half * 32, it1 = it0 + 32;

#pragma unroll
  for (int i = 0; i < 4; ++i)
    GLD16(&Ktile[(size_t)it0 * 8192 + (i * 256 + tid) * 8], &Ks[0][(i * 256 + tid) * 8]);
  asm volatile("s_waitcnt vmcnt(0)" ::: "memory");
  __syncthreads();

  for (int it = it0; it < it1; ++it) {
    const int cur = it & 1;
    if (it < it1 - 1) {
#pragma unroll
      for (int i = 0; i < 4; ++i)
        GLD16(&Ktile[(size_t)(it + 1) * 8192 + (i * 256 + tid) * 8],
              &Ks[cur ^ 1][(i * 256 + tid) * 8]);
    }

#pragma unroll
    for (int n = 0; n < 2; ++n) {
      f32x4 gh[4];
#pragma unroll
      for (int h = 0; h < 4; ++h) gh[h] = (f32x4){0.f, 0.f, 0.f, 0.f};
#pragma unroll
      for (int kk = 0; kk < 8; ++kk) {
        bf16x8 kb = *(const bf16x8*)&Ks[cur][(n * 16 + r15) * 256 + (((kk * 4 + g) ^ (r15 & 7)) << 3)];
        gh[0] = mfma16(*(const bf16x8*)&qr[0][kk], kb, gh[0]);
        gh[1] = mfma16(*(const bf16x8*)&qr[1][kk], kb, gh[1]);
        gh[2] = mfma16(*(const bf16x8*)&qr[2][kk], kb, gh[2]);
        gh[3] = mfma16(*(const bf16x8*)&qr[3][kk], kb, gh[3]);
      }
      float sn = 0.f;
#pragma unroll
      for (int h = 0; h < 4; ++h)
        sn += fexp2(gh[h][0]) + fexp2(gh[h][1]) + fexp2(gh[h][2]) + fexp2(gh[h][3]);
      sn += __shfl_xor(sn, 16);
      sn += __shfl_xor(sn, 32);
      if (g == 0)
        lpart[((size_t)((stile * 4 + w) * 32 + bh) << 11) + it * 32 + n * 16 + r15] = sn;
    }

    asm volatile("s_waitcnt vmcnt(0)" ::: "memory");
    __syncthreads();
  }
}

// ---------------- attention phase 1: s-tile 128, 3-ring GLD, counted vmcnt ----------------
// Ring of 3 K buffers; GLD(it+2) issued at top; fence = lgkmcnt(0) [Ps visible]
// + vmcnt(8) [drains GLD(it+1), keeps vb(it)+GLD(it+2) in flight] + raw s_barrier.
// In-order vmcnt retirement: issue order per iter = vb[4], GLD[4]; compiler's
// wait before PV's vb use drains to <=4 (never touches GLD(it+2)).
__global__ __launch_bounds__(256, 2) void attn_p1(
    const ushort* __restrict__ Qb, const ushort* __restrict__ Kb,
    const ushort* __restrict__ Vt, ushort* __restrict__ Zb)
{
  const int bid = blockIdx.x;
  const int swz = (bid & 7) * 64 + (bid >> 3);   // bijective: 512 % 8 == 0
  const int bh = swz >> 4, stile = swz & 15;
  const int s0 = stile * 128;
  const int tid = threadIdx.x, lane = tid & 63, w = tid >> 6;
  const int g = lane >> 4, r15 = lane & 15;

  __shared__ __align__(16) ushort Ks[3][8192];   // ring [32 t][256 k], swizzled
  __shared__ __align__(16) ushort Ps[2][5120];   // dbuf [128 s][40]

  bf16x8 q[2][8];
#pragma unroll
  for (int h = 0; h < 2; ++h) {
    const ushort* qrow = &Qb[((size_t)bh * 2048 + s0 + w * 32 + h * 16 + r15) * 256 + g * 8];
#pragma unroll
    for (int kk = 0; kk < 8; kk++) q[h][kk] = *(const bf16x8*)&qrow[kk * 32];
  }

  const ushort* Ktile = Kb + ((size_t)bh << 19);
  const ushort* Vtile = Vt + ((size_t)bh << 19);

  f32x4 acc[8][4];
#pragma unroll
  for (int m = 0; m < 8; m++)
#pragma unroll
    for (int n = 0; n < 4; n++) acc[m][n] = (f32x4){0.f, 0.f, 0.f, 0.f};

  // prologue: GLD K(0)->Ks[0], K(1)->Ks[1]; drain K(0) only; barrier
#pragma unroll
  for (int i = 0; i < 4; ++i)
    GLD16(&Ktile[(size_t)(i * 256 + tid) * 8], &Ks[0][(i * 256 + tid) * 8]);
#pragma unroll
  for (int i = 0; i < 4; ++i)
    GLD16(&Ktile[(size_t)8192 + (i * 256 + tid) * 8], &Ks[1][(i * 256 + tid) * 8]);
  asm volatile("s_waitcnt vmcnt(4)" ::: "memory");
  __builtin_amdgcn_s_barrier();
  __builtin_amdgcn_sched_barrier(0);

  for (int it = 0; it < 64; ++it) {
    const int kcur = it % 3;
    const int pcur = it & 1;
    // ---- vb(it) loads (to regs), then GLD(it+2) DMA (clamped tail: slot never read) ----
    bf16x8 vb[4];
#pragma unroll
    for (int n = 0; n < 4; ++n)
      vb[n] = *(const bf16x8*)&Vtile[(size_t)it * 8192 + (w * 64 + n * 16 + r15) * 32 + g * 8];
    {
      const int nx = it < 62 ? it + 2 : 63;
      const int knxt = (it + 2) % 3;
#pragma unroll
      for (int i = 0; i < 4; ++i)
        GLD16(&Ktile[(size_t)nx * 8192 + (i * 256 + tid) * 8],
              &Ks[knxt][(i * 256 + tid) * 8]);
    }

    // ---- QK^T: this wave's 32 s-rows x 32 t from Ks[kcur] -> Ps[pcur] ----
#pragma unroll
    for (int h = 0; h < 2; ++h) {
      f32x4 gg[2];
      gg[0] = (f32x4){0.f, 0.f, 0.f, 0.f};
      gg[1] = (f32x4){0.f, 0.f, 0.f, 0.f};
#pragma unroll
      for (int n = 0; n < 2; ++n)
#pragma unroll
        for (int kk = 0; kk < 8; ++kk) {
          bf16x8 kb = *(const bf16x8*)&Ks[kcur][(n * 16 + r15) * 256 + (((kk * 4 + g) ^ (r15 & 7)) << 3)];
          gg[n] = mfma16(q[h][kk], kb, gg[n]);
        }
#pragma unroll
      for (int n = 0; n < 2; ++n)
#pragma unroll
        for (int rr = 0; rr < 4; ++rr)
          Ps[pcur][(w * 32 + h * 16 + g * 4 + rr) * 40 + n * 16 + r15] = f2bf(fexp2(gg[n][rr]));
    }

    // ---- fence: Ps writes landed; K(it+1) landed; vb/GLD(it+2) stay in flight ----
    asm volatile("s_waitcnt lgkmcnt(0)" ::: "memory");
    asm volatile("s_waitcnt vmcnt(8)" ::: "memory");
    __builtin_amdgcn_s_barrier();
    __builtin_amdgcn_sched_barrier(0);

    // ---- PV: all 128 s x this wave's 64 e ----
#pragma unroll
    for (int mh = 0; mh < 2; ++mh) {
      bf16x8 pa[4];
#pragma unroll
      for (int m = 0; m < 4; ++m)
        pa[m] = *(const bf16x8*)&Ps[pcur][((mh * 4 + m) * 16 + r15) * 40 + g * 8];
#pragma unroll
      for (int n = 0; n < 4; ++n)
#pragma unroll
        for (int m = 0; m < 4; ++m)
          acc[mh * 4 + m][n] = mfma16(pa[m], vb[n], acc[mh * 4 + m][n]);
    }
  }

  const int b = bh >> 3, h = bh & 7;
#pragma unroll
  for (int m = 0; m < 8; m++)
#pragma unroll
    for (int n = 0; n < 4; n++)
#pragma unroll
      for (int rr = 0; rr < 4; rr++) {
        int sl = m * 16 + g * 4 + rr;
        int el = w * 64 + n * 16 + r15;
        Zb[((size_t)(b * 2048 + s0 + sl)) * 2048 + h * 256 + el] = f2bf(acc[m][n][rr]);
      }
}

// ---------------- V' in-place scale by 1/l_t (32 partials) ----------------
__global__ __launch_bounds__(256) void vscale(
    ushort* __restrict__ Vt, const float* __restrict__ lp)
{
  const int tt = blockIdx.x, bh = blockIdx.y, tid = threadIdx.x;
  const int t = tid & 31, pg = tid >> 5;
  __shared__ float red[256];
  __shared__ float cinv[32];
  float s = 0.f;
  for (int p = pg * 4; p < pg * 4 + 4; ++p)
    s += lp[(((size_t)p * 32 + bh) << 11) + tt * 32 + t];
  red[tid] = s;
  __syncthreads();
  if (tid < 32) {
    float tot = 0.f;
#pragma unroll
    for (int i = 0; i < 8; ++i) tot += red[tid + i * 32];
    cinv[tid] = 1.0f / tot;
  }
  __syncthreads();
  size_t base = (((size_t)bh * 64 + tt) << 13) + (size_t)tid * 32;
  ushort buf[32];
#pragma unroll
  for (int i = 0; i < 4; ++i) *(uint4*)&buf[i * 8] = *(const uint4*)&Vt[base + i * 8];
#pragma unroll
  for (int j = 0; j < 32; ++j) buf[j] = f2bf(bf2f(buf[j]) * cinv[j]);
#pragma unroll
  for (int i = 0; i < 4; ++i) *(uint4*)&Vt[base + i * 8] = *(const uint4*)&buf[i * 8];
}

// ---------------- launch ----------------
extern "C" void kernel_launch(void* const* d_in, const int* in_sizes, int n_in,
                              void* d_out, int out_size, void* d_ws, size_t ws_size,
                              hipStream_t stream) {
  const float* x  = (const float*)d_in[0];
  const float* Wq = (const float*)d_in[1];
  const float* bq = (const float*)d_in[2];
  const float* Wk = (const float*)d_in[3];
  const float* bk = (const float*)d_in[4];
  const float* Wv = (const float*)d_in[5];
  const float* bv = (const float*)d_in[6];
  const float* Wo = (const float*)d_in[7];
  const float* bo = (const float*)d_in[8];

  if (ws_size < (size_t)176160768) return; // need 168 MB scratch

  char* ws = (char*)d_ws;
  ushort* bfb = (ushort*)ws;                       // bf16 conversions (8 MB)
  ushort* xb  = bfb;
  ushort* wqb = bfb + 2097152;
  ushort* wkb = bfb + 2621440;
  ushort* wvb = bfb + 3145728;
  ushort* wob = bfb + 3670016;
  ushort* Qb = (ushort*)(ws + 8388608);            // [32,2048,256] (Q pre-scaled log2e/16)
  ushort* Kb = (ushort*)(ws + 41943040);           // [32,2048,256] T2-swizzled
  ushort* Vt = (ushort*)(ws + 75497472);           // [32,64,256,32] tiled V'
  ushort* Zb = (ushort*)(ws + 109051904);          // [8192,2048]
  float*  lp = (float*)(ws + 142606336);           // [32,32,2048] fp32 partial colsums
  float* out = (float*)d_out;

  convert_all<<<4096, 256, 0, stream>>>(x, Wq, Wk, Wv, Wo, bfb);
  gemm_qkv<128, 128><<<dim3(48, 64), 256, 0, stream>>>(
      xb, wqb, wkb, wvb, 256, bq, bk, bv, Qb, Kb, Vt);
  attn_p0<<<512, 256, 0, stream>>>(Qb, Kb, lp);
  vscale<<<dim3(64, 32), 256, 0, stream>>>(Vt, lp);
  attn_p1<<<512, 256, 0, stream>>>(Qb, Kb, Vt, Zb);
  gemm_out<<<dim3(4, 128), 256, 0, stream>>>(Zb, wob, bo, out);
}

// Round 25
// 319.062 us; speedup vs baseline: 1.6406x; 1.6406x over previous
//
#include <hip/hip_runtime.h>
#include <hip/hip_bf16.h>

#define DEV __device__ __forceinline__

typedef __bf16 bf16x8 __attribute__((ext_vector_type(8)));
typedef float f32x4 __attribute__((ext_vector_type(4)));

DEV f32x4 mfma16(bf16x8 a, bf16x8 b, f32x4 c) {
  return __builtin_amdgcn_mfma_f32_16x16x32_bf16(a, b, c, 0, 0, 0);
}

DEV ushort f2bf(float f) {
  union { __hip_bfloat16 h; ushort u; } cv;
  cv.h = __float2bfloat16(f);
  return cv.u;
}
DEV float bf2f(ushort u) {
  union { float f; unsigned v; } cv; cv.v = ((unsigned)u) << 16; return cv.f;
}

// bare v_exp_f32 (2^x): no mul, no libm guards (r20/r21 lesson)
DEV float fexp2(float x) { return __builtin_amdgcn_exp2f(x); }

// async global->LDS, 16B/lane; LDS dest linear in lane
#define GLD16(gp, lp)                                                              \
  __builtin_amdgcn_global_load_lds(                                                \
      (const __attribute__((address_space(1))) unsigned int*)(gp),                 \
      (__attribute__((address_space(3))) unsigned int*)(lp), 16, 0, 0)

// ---------------- constants ----------------
// B=4 H=8 S=2048 D=256; BH=32; M=B*S=8192
// Q pre-scaled by log2(e)/16 so attention exp is a single v_exp_f32.
// K global layout: [bh][t][256] bf16, pre-swizzled: chunk(e>>3) ^= (t&7)
// V global layout: [bh][ttile=t/32][256 e][32 t] bf16 tiles, scaled 1/l_t (vscale)
// lp: [32 partials][32 bh][2048 t] fp32
// r24 lesson: counted-vmcnt ring in p1 = 6x L2 overfetch (FETCH 49->309MB),
//   134->322us — 3rd counted-vmcnt failure; needs full 8-phase co-design, does
//   NOT graft onto 2-barrier structures. qkv BK=128 also regressed (+15us).
// r25 = r23 exact (320.4us best): p1 GLD-dbuf vmcnt(0) fence, qkv BK=64.

// ---------------- kernel A: fp32 -> bf16 conversion ----------------
__global__ __launch_bounds__(256) void convert_all(
    const float* __restrict__ x, const float* __restrict__ wq,
    const float* __restrict__ wk, const float* __restrict__ wv,
    const float* __restrict__ wo, ushort* __restrict__ dst)
{
  size_t i = ((size_t)blockIdx.x * 256 + threadIdx.x) * 4;
  const float* src; size_t off;
  if (i < (size_t)2097152) { src = x; off = i; }
  else {
    size_t j = i - 2097152;
    unsigned wsel = (unsigned)(j >> 19);
    off = j & 524287;
    src = wsel == 0 ? wq : wsel == 1 ? wk : wsel == 2 ? wv : wo;
  }
  float4 v = *(const float4*)(src + off);
  ushort4 o;
  o.x = f2bf(v.x); o.y = f2bf(v.y); o.z = f2bf(v.z); o.w = f2bf(v.w);
  *(ushort4*)(dst + i) = o;
}

// ---------------- QKV GEMM (NT), BK=64 (r16, proven) ----------------
template<int BM, int BN>
__global__ __launch_bounds__(256, 2) void gemm_qkv(
    const ushort* __restrict__ A,
    const ushort* __restrict__ W0, const ushort* __restrict__ W1, const ushort* __restrict__ W2,
    int K,
    const float* __restrict__ b0, const float* __restrict__ b1, const float* __restrict__ b2,
    ushort* __restrict__ Qo, ushort* __restrict__ Ko, ushort* __restrict__ Vo)
{
  constexpr int WM = BM / 2, WN = BN / 2, MF = WM / 16, NF = WN / 16;
  const int n0 = blockIdx.x * BN, m0 = blockIdx.y * BM;
  const int tid = threadIdx.x, lane = tid & 63;
  const int wm = (tid >> 7) & 1, wn = (tid >> 6) & 1;
  const int g = lane >> 4, r15 = lane & 15;

  __shared__ ushort As[BM * 72];
  __shared__ ushort Bs[BN * 72];

  const int p = n0 >> 11;
  const ushort* Bt = (p == 0 ? W0 : p == 1 ? W1 : W2) + (size_t)(n0 & 2047) * K;

  f32x4 acc[MF][NF];
#pragma unroll
  for (int m = 0; m < MF; m++)
#pragma unroll
    for (int n = 0; n < NF; n++) acc[m][n] = (f32x4){0.f, 0.f, 0.f, 0.f};

  for (int k0 = 0; k0 < K; k0 += 64) {
#pragma unroll
    for (int i = 0; i < 4; i++) {
      int ci = tid * 4 + i; int r = ci >> 3, c = ci & 7;
      *(uint4*)&As[r * 72 + c * 8] = *(const uint4*)&A[(size_t)(m0 + r) * K + k0 + c * 8];
      *(uint4*)&Bs[r * 72 + c * 8] = *(const uint4*)&Bt[(size_t)r * K + k0 + c * 8];
    }
    __syncthreads();
    bf16x8 af[MF][2], bfr[NF][2];
#pragma unroll
    for (int m = 0; m < MF; m++)
#pragma unroll
      for (int k2 = 0; k2 < 2; ++k2)
        af[m][k2] = *(const bf16x8*)&As[(wm * WM + m * 16 + r15) * 72 + k2 * 32 + g * 8];
#pragma unroll
    for (int n = 0; n < NF; n++)
#pragma unroll
      for (int k2 = 0; k2 < 2; ++k2)
        bfr[n][k2] = *(const bf16x8*)&Bs[(wn * WN + n * 16 + r15) * 72 + k2 * 32 + g * 8];
#pragma unroll
    for (int k2 = 0; k2 < 2; ++k2)
#pragma unroll
      for (int m = 0; m < MF; m++)
#pragma unroll
        for (int n = 0; n < NF; n++) acc[m][n] = mfma16(af[m][k2], bfr[n][k2], acc[m][n]);
    __syncthreads();
  }

  const float* bias = (p == 0 ? b0 : p == 1 ? b1 : b2);
  const float scl = (p == 0 ? 0.0625f * 1.44269504088896f : 1.0f);
#pragma unroll
  for (int m = 0; m < MF; m++)
#pragma unroll
    for (int n = 0; n < NF; n++)
#pragma unroll
      for (int r = 0; r < 4; r++) {
        int row = m0 + wm * WM + m * 16 + g * 4 + r;
        int col = n0 + wn * WN + n * 16 + r15;
        int ce = col & 2047;
        float v = (acc[m][n][r] + bias[ce]) * scl;
        int b = row >> 11, s = row & 2047, h = ce >> 8, e = ce & 255;
        int bh = b * 8 + h;
        if (p == 0) {
          Qo[((size_t)(bh * 2048 + s) << 8) + e] = f2bf(v);
        } else if (p == 1) {
          int ee = ((((e >> 3) ^ (s & 7)) & 31) << 3) | (e & 7); // T2 pre-swizzle
          Ko[((size_t)(bh * 2048 + s) << 8) + ee] = f2bf(v);
        } else {
          Vo[(((size_t)bh * 64 + (s >> 5)) << 13) + e * 32 + (s & 31)] = f2bf(v);
        }
      }
}

// ---------------- out GEMM ----------------
__global__ __launch_bounds__(256, 2) void gemm_out(
    const ushort* __restrict__ A, const ushort* __restrict__ Bw,
    const float* __restrict__ bias, float* __restrict__ out)
{
  const int n0 = blockIdx.x * 64, m0 = blockIdx.y * 64;
  const int tid = threadIdx.x, lane = tid & 63;
  const int wm = (tid >> 7) & 1, wn = (tid >> 6) & 1;
  const int g = lane >> 4, r15 = lane & 15;

  __shared__ ushort As[64 * 72];
  __shared__ ushort Bs[64 * 72];

  f32x4 acc[2][2];
#pragma unroll
  for (int m = 0; m < 2; m++)
#pragma unroll
    for (int n = 0; n < 2; n++) acc[m][n] = (f32x4){0.f, 0.f, 0.f, 0.f};

  for (int k0 = 0; k0 < 2048; k0 += 64) {
#pragma unroll
    for (int i = 0; i < 2; ++i) {
      int ci = tid * 2 + i, r = ci >> 3, c = ci & 7;
      *(uint4*)&As[r * 72 + c * 8] = *(const uint4*)&A[(size_t)(m0 + r) * 2048 + k0 + c * 8];
      *(uint4*)&Bs[r * 72 + c * 8] = *(const uint4*)&Bw[(size_t)(n0 + r) * 2048 + k0 + c * 8];
    }
    __syncthreads();
    bf16x8 af[2][2], bfr[2][2];
#pragma unroll
    for (int m = 0; m < 2; ++m)
#pragma unroll
      for (int k2 = 0; k2 < 2; ++k2)
        af[m][k2] = *(const bf16x8*)&As[(wm * 32 + m * 16 + r15) * 72 + k2 * 32 + g * 8];
#pragma unroll
    for (int n = 0; n < 2; ++n)
#pragma unroll
      for (int k2 = 0; k2 < 2; ++k2)
        bfr[n][k2] = *(const bf16x8*)&Bs[(wn * 32 + n * 16 + r15) * 72 + k2 * 32 + g * 8];
#pragma unroll
    for (int k2 = 0; k2 < 2; ++k2)
#pragma unroll
      for (int m = 0; m < 2; ++m)
#pragma unroll
        for (int n = 0; n < 2; ++n)
          acc[m][n] = mfma16(af[m][k2], bfr[n][k2], acc[m][n]);
    __syncthreads();
  }

#pragma unroll
  for (int m = 0; m < 2; m++)
#pragma unroll
    for (int n = 0; n < 2; n++)
#pragma unroll
      for (int r = 0; r < 4; r++) {
        int row = m0 + wm * 32 + m * 16 + g * 4 + r;
        int col = n0 + wn * 32 + n * 16 + r15;
        out[(size_t)row * 256 + col] = acc[m][n][r] + bias[col];
      }
}

// ---------------- attention phase 0: s-tile 256, GLD dbuf, one barrier (r22, proven) ----------------
__global__ __launch_bounds__(256, 2) void attn_p0(
    const ushort* __restrict__ Qb, const ushort* __restrict__ Kb,
    float* __restrict__ lpart)
{
  const int bid = blockIdx.x;
  const int swz = (bid & 7) * 64 + (bid >> 3);   // bijective: 512 % 8 == 0
  const int bh = swz >> 4, stile = (swz >> 1) & 7, half = swz & 1;
  const int s0 = stile * 256;
  const int tid = threadIdx.x, lane = tid & 63, w = tid >> 6;
  const int g = lane >> 4, r15 = lane & 15;

  __shared__ __align__(16) ushort Ks[2][8192];   // dbuf [32 t][256 k], swizzled

  uint4 qr[4][8];
#pragma unroll
  for (int h = 0; h < 4; ++h) {
    const ushort* qrow = &Qb[((size_t)bh * 2048 + s0 + w * 64 + h * 16 + r15) * 256 + g * 8];
#pragma unroll
    for (int kk = 0; kk < 8; kk++) qr[h][kk] = *(const uint4*)&qrow[kk * 32];
  }
#pragma unroll
  for (int h = 0; h < 4; ++h)
#pragma unroll
    for (int kk = 0; kk < 8; kk++)
      asm volatile("" : "+v"(qr[h][kk].x), "+v"(qr[h][kk].y),
                        "+v"(qr[h][kk].z), "+v"(qr[h][kk].w));

  const ushort* Ktile = Kb + ((size_t)bh << 19);
  const int it0 = half * 32, it1 = it0 + 32;

#pragma unroll
  for (int i = 0; i < 4; ++i)
    GLD16(&Ktile[(size_t)it0 * 8192 + (i * 256 + tid) * 8], &Ks[0][(i * 256 + tid) * 8]);
  asm volatile("s_waitcnt vmcnt(0)" ::: "memory");
  __syncthreads();

  for (int it = it0; it < it1; ++it) {
    const int cur = it & 1;
    if (it < it1 - 1) {
#pragma unroll
      for (int i = 0; i < 4; ++i)
        GLD16(&Ktile[(size_t)(it + 1) * 8192 + (i * 256 + tid) * 8],
              &Ks[cur ^ 1][(i * 256 + tid) * 8]);
    }

#pragma unroll
    for (int n = 0; n < 2; ++n) {
      f32x4 gh[4];
#pragma unroll
      for (int h = 0; h < 4; ++h) gh[h] = (f32x4){0.f, 0.f, 0.f, 0.f};
#pragma unroll
      for (int kk = 0; kk < 8; ++kk) {
        bf16x8 kb = *(const bf16x8*)&Ks[cur][(n * 16 + r15) * 256 + (((kk * 4 + g) ^ (r15 & 7)) << 3)];
        gh[0] = mfma16(*(const bf16x8*)&qr[0][kk], kb, gh[0]);
        gh[1] = mfma16(*(const bf16x8*)&qr[1][kk], kb, gh[1]);
        gh[2] = mfma16(*(const bf16x8*)&qr[2][kk], kb, gh[2]);
        gh[3] = mfma16(*(const bf16x8*)&qr[3][kk], kb, gh[3]);
      }
      float sn = 0.f;
#pragma unroll
      for (int h = 0; h < 4; ++h)
        sn += fexp2(gh[h][0]) + fexp2(gh[h][1]) + fexp2(gh[h][2]) + fexp2(gh[h][3]);
      sn += __shfl_xor(sn, 16);
      sn += __shfl_xor(sn, 32);
      if (g == 0)
        lpart[((size_t)((stile * 4 + w) * 32 + bh) << 11) + it * 32 + n * 16 + r15] = sn;
    }

    asm volatile("s_waitcnt vmcnt(0)" ::: "memory");
    __syncthreads();
  }
}

// ---------------- attention phase 1: s-tile 128, GLD K staging, one barrier (r23, proven) ----------------
__global__ __launch_bounds__(256, 2) void attn_p1(
    const ushort* __restrict__ Qb, const ushort* __restrict__ Kb,
    const ushort* __restrict__ Vt, ushort* __restrict__ Zb)
{
  const int bid = blockIdx.x;
  const int swz = (bid & 7) * 64 + (bid >> 3);   // bijective: 512 % 8 == 0
  const int bh = swz >> 4, stile = swz & 15;
  const int s0 = stile * 128;
  const int tid = threadIdx.x, lane = tid & 63, w = tid >> 6;
  const int g = lane >> 4, r15 = lane & 15;

  __shared__ __align__(16) ushort Ks[2][8192];
  __shared__ __align__(16) ushort Ps[2][5120];

  bf16x8 q[2][8];
#pragma unroll
  for (int h = 0; h < 2; ++h) {
    const ushort* qrow = &Qb[((size_t)bh * 2048 + s0 + w * 32 + h * 16 + r15) * 256 + g * 8];
#pragma unroll
    for (int kk = 0; kk < 8; kk++) q[h][kk] = *(const bf16x8*)&qrow[kk * 32];
  }

  const ushort* Ktile = Kb + ((size_t)bh << 19);
  const ushort* Vtile = Vt + ((size_t)bh << 19);

  f32x4 acc[8][4];
#pragma unroll
  for (int m = 0; m < 8; m++)
#pragma unroll
    for (int n = 0; n < 4; n++) acc[m][n] = (f32x4){0.f, 0.f, 0.f, 0.f};

  // prologue: DMA K(0) -> Ks[0], fence, barrier
#pragma unroll
  for (int i = 0; i < 4; ++i)
    GLD16(&Ktile[(size_t)(i * 256 + tid) * 8], &Ks[0][(i * 256 + tid) * 8]);
  asm volatile("s_waitcnt vmcnt(0)" ::: "memory");
  __syncthreads();

  for (int it = 0; it < 64; ++it) {
    const int cur = it & 1;
    // ---- top clump: V(it) frags (to regs) + K(it+1) DMA (to LDS) ----
    bf16x8 vb[4];
#pragma unroll
    for (int n = 0; n < 4; ++n)
      vb[n] = *(const bf16x8*)&Vtile[(size_t)it * 8192 + (w * 64 + n * 16 + r15) * 32 + g * 8];
    if (it < 63) {
#pragma unroll
      for (int i = 0; i < 4; ++i)
        GLD16(&Ktile[(size_t)(it + 1) * 8192 + (i * 256 + tid) * 8],
              &Ks[cur ^ 1][(i * 256 + tid) * 8]);
    }

    // ---- QK^T: this wave's 32 s-rows x 32 t from Ks[cur] ----
#pragma unroll
    for (int h = 0; h < 2; ++h) {
      f32x4 gg[2];
      gg[0] = (f32x4){0.f, 0.f, 0.f, 0.f};
      gg[1] = (f32x4){0.f, 0.f, 0.f, 0.f};
#pragma unroll
      for (int n = 0; n < 2; ++n)
#pragma unroll
        for (int kk = 0; kk < 8; ++kk) {
          bf16x8 kb = *(const bf16x8*)&Ks[cur][(n * 16 + r15) * 256 + (((kk * 4 + g) ^ (r15 & 7)) << 3)];
          gg[n] = mfma16(q[h][kk], kb, gg[n]);
        }
#pragma unroll
      for (int n = 0; n < 2; ++n)
#pragma unroll
        for (int rr = 0; rr < 4; ++rr)
          Ps[cur][(w * 32 + h * 16 + g * 4 + rr) * 40 + n * 16 + r15] = f2bf(fexp2(gg[n][rr]));
    }

    // ---- fence: K(it+1) DMA landed (r3-fix) + vb complete; then ONE barrier ----
    asm volatile("s_waitcnt vmcnt(0)" ::: "memory");
    __syncthreads();

    // ---- PV: all 128 s x this wave's 64 e ----
#pragma unroll
    for (int mh = 0; mh < 2; ++mh) {
      bf16x8 pa[4];
#pragma unroll
      for (int m = 0; m < 4; ++m)
        pa[m] = *(const bf16x8*)&Ps[cur][((mh * 4 + m) * 16 + r15) * 40 + g * 8];
#pragma unroll
      for (int n = 0; n < 4; ++n)
#pragma unroll
        for (int m = 0; m < 4; ++m)
          acc[mh * 4 + m][n] = mfma16(pa[m], vb[n], acc[mh * 4 + m][n]);
    }
  }

  const int b = bh >> 3, h = bh & 7;
#pragma unroll
  for (int m = 0; m < 8; m++)
#pragma unroll
    for (int n = 0; n < 4; n++)
#pragma unroll
      for (int rr = 0; rr < 4; rr++) {
        int sl = m * 16 + g * 4 + rr;
        int el = w * 64 + n * 16 + r15;
        Zb[((size_t)(b * 2048 + s0 + sl)) * 2048 + h * 256 + el] = f2bf(acc[m][n][rr]);
      }
}

// ---------------- V' in-place scale by 1/l_t (32 partials) ----------------
__global__ __launch_bounds__(256) void vscale(
    ushort* __restrict__ Vt, const float* __restrict__ lp)
{
  const int tt = blockIdx.x, bh = blockIdx.y, tid = threadIdx.x;
  const int t = tid & 31, pg = tid >> 5;
  __shared__ float red[256];
  __shared__ float cinv[32];
  float s = 0.f;
  for (int p = pg * 4; p < pg * 4 + 4; ++p)
    s += lp[(((size_t)p * 32 + bh) << 11) + tt * 32 + t];
  red[tid] = s;
  __syncthreads();
  if (tid < 32) {
    float tot = 0.f;
#pragma unroll
    for (int i = 0; i < 8; ++i) tot += red[tid + i * 32];
    cinv[tid] = 1.0f / tot;
  }
  __syncthreads();
  size_t base = (((size_t)bh * 64 + tt) << 13) + (size_t)tid * 32;
  ushort buf[32];
#pragma unroll
  for (int i = 0; i < 4; ++i) *(uint4*)&buf[i * 8] = *(const uint4*)&Vt[base + i * 8];
#pragma unroll
  for (int j = 0; j < 32; ++j) buf[j] = f2bf(bf2f(buf[j]) * cinv[j]);
#pragma unroll
  for (int i = 0; i < 4; ++i) *(uint4*)&Vt[base + i * 8] = *(const uint4*)&buf[i * 8];
}

// ---------------- launch ----------------
extern "C" void kernel_launch(void* const* d_in, const int* in_sizes, int n_in,
                              void* d_out, int out_size, void* d_ws, size_t ws_size,
                              hipStream_t stream) {
  const float* x  = (const float*)d_in[0];
  const float* Wq = (const float*)d_in[1];
  const float* bq = (const float*)d_in[2];
  const float* Wk = (const float*)d_in[3];
  const float* bk = (const float*)d_in[4];
  const float* Wv = (const float*)d_in[5];
  const float* bv = (const float*)d_in[6];
  const float* Wo = (const float*)d_in[7];
  const float* bo = (const float*)d_in[8];

  if (ws_size < (size_t)176160768) return; // need 168 MB scratch

  char* ws = (char*)d_ws;
  ushort* bfb = (ushort*)ws;                       // bf16 conversions (8 MB)
  ushort* xb  = bfb;
  ushort* wqb = bfb + 2097152;
  ushort* wkb = bfb + 2621440;
  ushort* wvb = bfb + 3145728;
  ushort* wob = bfb + 3670016;
  ushort* Qb = (ushort*)(ws + 8388608);            // [32,2048,256] (Q pre-scaled log2e/16)
  ushort* Kb = (ushort*)(ws + 41943040);           // [32,2048,256] T2-swizzled
  ushort* Vt = (ushort*)(ws + 75497472);           // [32,64,256,32] tiled V'
  ushort* Zb = (ushort*)(ws + 109051904);          // [8192,2048]
  float*  lp = (float*)(ws + 142606336);           // [32,32,2048] fp32 partial colsums
  float* out = (float*)d_out;

  convert_all<<<4096, 256, 0, stream>>>(x, Wq, Wk, Wv, Wo, bfb);
  gemm_qkv<128, 128><<<dim3(48, 64), 256, 0, stream>>>(
      xb, wqb, wkb, wvb, 256, bq, bk, bv, Qb, Kb, Vt);
  attn_p0<<<512, 256, 0, stream>>>(Qb, Kb, lp);
  vscale<<<dim3(64, 32), 256, 0, stream>>>(Vt, lp);
  attn_p1<<<512, 256, 0, stream>>>(Qb, Kb, Vt, Zb);
  gemm_out<<<dim3(4, 128), 256, 0, stream>>>(Zb, wob, bo, out);
}

// Round 26
// 318.502 us; speedup vs baseline: 1.6435x; 1.0018x over previous
//
#include <hip/hip_runtime.h>
#include <hip/hip_bf16.h>

#define DEV __device__ __forceinline__

typedef __bf16 bf16x8 __attribute__((ext_vector_type(8)));
typedef float f32x4 __attribute__((ext_vector_type(4)));

DEV f32x4 mfma16(bf16x8 a, bf16x8 b, f32x4 c) {
  return __builtin_amdgcn_mfma_f32_16x16x32_bf16(a, b, c, 0, 0, 0);
}

DEV ushort f2bf(float f) {
  union { __hip_bfloat16 h; ushort u; } cv;
  cv.h = __float2bfloat16(f);
  return cv.u;
}
DEV float bf2f(ushort u) {
  union { float f; unsigned v; } cv; cv.v = ((unsigned)u) << 16; return cv.f;
}

// bare v_exp_f32 (2^x): no mul, no libm guards (r20/r21 lesson)
DEV float fexp2(float x) { return __builtin_amdgcn_exp2f(x); }

// async global->LDS, 16B/lane; LDS dest linear in lane
#define GLD16(gp, lp)                                                              \
  __builtin_amdgcn_global_load_lds(                                                \
      (const __attribute__((address_space(1))) unsigned int*)(gp),                 \
      (__attribute__((address_space(3))) unsigned int*)(lp), 16, 0, 0)

// ---------------- constants ----------------
// B=4 H=8 S=2048 D=256; BH=32; M=B*S=8192
// Q pre-scaled by log2(e)/16 so attention exp is a single v_exp_f32.
// K global layout: [bh][t][256] bf16, pre-swizzled: chunk(e>>3) ^= (t&7)
// V global layout: [bh][ttile=t/32][256 e][32 t] bf16 tiles, scaled 1/l_t (vscale)
// lp: [32 partials][32 bh][2048 t] fp32
// r24/r25 lessons: counted-vmcnt does NOT graft onto 2-barrier structures
//   (3 failures: r19/r24); qkv BK=64 is the sweet spot; r23 structure = 319us.
// r26: p0 t-tile 32->64 (16 iters, half the fence stalls + barriers; LDS 64KB
//   still 2/CU; no V-coalescing concern unlike r6's p1 attempt).

// ---------------- kernel A: fp32 -> bf16 conversion ----------------
__global__ __launch_bounds__(256) void convert_all(
    const float* __restrict__ x, const float* __restrict__ wq,
    const float* __restrict__ wk, const float* __restrict__ wv,
    const float* __restrict__ wo, ushort* __restrict__ dst)
{
  size_t i = ((size_t)blockIdx.x * 256 + threadIdx.x) * 4;
  const float* src; size_t off;
  if (i < (size_t)2097152) { src = x; off = i; }
  else {
    size_t j = i - 2097152;
    unsigned wsel = (unsigned)(j >> 19);
    off = j & 524287;
    src = wsel == 0 ? wq : wsel == 1 ? wk : wsel == 2 ? wv : wo;
  }
  float4 v = *(const float4*)(src + off);
  ushort4 o;
  o.x = f2bf(v.x); o.y = f2bf(v.y); o.z = f2bf(v.z); o.w = f2bf(v.w);
  *(ushort4*)(dst + i) = o;
}

// ---------------- QKV GEMM (NT), BK=64 (r16, proven) ----------------
template<int BM, int BN>
__global__ __launch_bounds__(256, 2) void gemm_qkv(
    const ushort* __restrict__ A,
    const ushort* __restrict__ W0, const ushort* __restrict__ W1, const ushort* __restrict__ W2,
    int K,
    const float* __restrict__ b0, const float* __restrict__ b1, const float* __restrict__ b2,
    ushort* __restrict__ Qo, ushort* __restrict__ Ko, ushort* __restrict__ Vo)
{
  constexpr int WM = BM / 2, WN = BN / 2, MF = WM / 16, NF = WN / 16;
  const int n0 = blockIdx.x * BN, m0 = blockIdx.y * BM;
  const int tid = threadIdx.x, lane = tid & 63;
  const int wm = (tid >> 7) & 1, wn = (tid >> 6) & 1;
  const int g = lane >> 4, r15 = lane & 15;

  __shared__ ushort As[BM * 72];
  __shared__ ushort Bs[BN * 72];

  const int p = n0 >> 11;
  const ushort* Bt = (p == 0 ? W0 : p == 1 ? W1 : W2) + (size_t)(n0 & 2047) * K;

  f32x4 acc[MF][NF];
#pragma unroll
  for (int m = 0; m < MF; m++)
#pragma unroll
    for (int n = 0; n < NF; n++) acc[m][n] = (f32x4){0.f, 0.f, 0.f, 0.f};

  for (int k0 = 0; k0 < K; k0 += 64) {
#pragma unroll
    for (int i = 0; i < 4; i++) {
      int ci = tid * 4 + i; int r = ci >> 3, c = ci & 7;
      *(uint4*)&As[r * 72 + c * 8] = *(const uint4*)&A[(size_t)(m0 + r) * K + k0 + c * 8];
      *(uint4*)&Bs[r * 72 + c * 8] = *(const uint4*)&Bt[(size_t)r * K + k0 + c * 8];
    }
    __syncthreads();
    bf16x8 af[MF][2], bfr[NF][2];
#pragma unroll
    for (int m = 0; m < MF; m++)
#pragma unroll
      for (int k2 = 0; k2 < 2; ++k2)
        af[m][k2] = *(const bf16x8*)&As[(wm * WM + m * 16 + r15) * 72 + k2 * 32 + g * 8];
#pragma unroll
    for (int n = 0; n < NF; n++)
#pragma unroll
      for (int k2 = 0; k2 < 2; ++k2)
        bfr[n][k2] = *(const bf16x8*)&Bs[(wn * WN + n * 16 + r15) * 72 + k2 * 32 + g * 8];
#pragma unroll
    for (int k2 = 0; k2 < 2; ++k2)
#pragma unroll
      for (int m = 0; m < MF; m++)
#pragma unroll
        for (int n = 0; n < NF; n++) acc[m][n] = mfma16(af[m][k2], bfr[n][k2], acc[m][n]);
    __syncthreads();
  }

  const float* bias = (p == 0 ? b0 : p == 1 ? b1 : b2);
  const float scl = (p == 0 ? 0.0625f * 1.44269504088896f : 1.0f);
#pragma unroll
  for (int m = 0; m < MF; m++)
#pragma unroll
    for (int n = 0; n < NF; n++)
#pragma unroll
      for (int r = 0; r < 4; r++) {
        int row = m0 + wm * WM + m * 16 + g * 4 + r;
        int col = n0 + wn * WN + n * 16 + r15;
        int ce = col & 2047;
        float v = (acc[m][n][r] + bias[ce]) * scl;
        int b = row >> 11, s = row & 2047, h = ce >> 8, e = ce & 255;
        int bh = b * 8 + h;
        if (p == 0) {
          Qo[((size_t)(bh * 2048 + s) << 8) + e] = f2bf(v);
        } else if (p == 1) {
          int ee = ((((e >> 3) ^ (s & 7)) & 31) << 3) | (e & 7); // T2 pre-swizzle
          Ko[((size_t)(bh * 2048 + s) << 8) + ee] = f2bf(v);
        } else {
          Vo[(((size_t)bh * 64 + (s >> 5)) << 13) + e * 32 + (s & 31)] = f2bf(v);
        }
      }
}

// ---------------- out GEMM ----------------
__global__ __launch_bounds__(256, 2) void gemm_out(
    const ushort* __restrict__ A, const ushort* __restrict__ Bw,
    const float* __restrict__ bias, float* __restrict__ out)
{
  const int n0 = blockIdx.x * 64, m0 = blockIdx.y * 64;
  const int tid = threadIdx.x, lane = tid & 63;
  const int wm = (tid >> 7) & 1, wn = (tid >> 6) & 1;
  const int g = lane >> 4, r15 = lane & 15;

  __shared__ ushort As[64 * 72];
  __shared__ ushort Bs[64 * 72];

  f32x4 acc[2][2];
#pragma unroll
  for (int m = 0; m < 2; m++)
#pragma unroll
    for (int n = 0; n < 2; n++) acc[m][n] = (f32x4){0.f, 0.f, 0.f, 0.f};

  for (int k0 = 0; k0 < 2048; k0 += 64) {
#pragma unroll
    for (int i = 0; i < 2; ++i) {
      int ci = tid * 2 + i, r = ci >> 3, c = ci & 7;
      *(uint4*)&As[r * 72 + c * 8] = *(const uint4*)&A[(size_t)(m0 + r) * 2048 + k0 + c * 8];
      *(uint4*)&Bs[r * 72 + c * 8] = *(const uint4*)&Bw[(size_t)(n0 + r) * 2048 + k0 + c * 8];
    }
    __syncthreads();
    bf16x8 af[2][2], bfr[2][2];
#pragma unroll
    for (int m = 0; m < 2; ++m)
#pragma unroll
      for (int k2 = 0; k2 < 2; ++k2)
        af[m][k2] = *(const bf16x8*)&As[(wm * 32 + m * 16 + r15) * 72 + k2 * 32 + g * 8];
#pragma unroll
    for (int n = 0; n < 2; ++n)
#pragma unroll
      for (int k2 = 0; k2 < 2; ++k2)
        bfr[n][k2] = *(const bf16x8*)&Bs[(wn * 32 + n * 16 + r15) * 72 + k2 * 32 + g * 8];
#pragma unroll
    for (int k2 = 0; k2 < 2; ++k2)
#pragma unroll
      for (int m = 0; m < 2; ++m)
#pragma unroll
        for (int n = 0; n < 2; ++n)
          acc[m][n] = mfma16(af[m][k2], bfr[n][k2], acc[m][n]);
    __syncthreads();
  }

#pragma unroll
  for (int m = 0; m < 2; m++)
#pragma unroll
    for (int n = 0; n < 2; n++)
#pragma unroll
      for (int r = 0; r < 4; r++) {
        int row = m0 + wm * 32 + m * 16 + g * 4 + r;
        int col = n0 + wn * 32 + n * 16 + r15;
        out[(size_t)row * 256 + col] = acc[m][n][r] + bias[col];
      }
}

// ---------------- attention phase 0: s-tile 256, t-tile 64, GLD dbuf ----------------
// grid 512 XCD-swizzled (32bh x 8stile x 2thalf) = 2 blocks/CU; 16 iters of 64 t.
// Per iter: 8 GLD16 (32KB tile) -> compute 128 MFMA + exp/colsum -> fence -> barrier.
// Half the fence stalls/barriers of the 32-t version; same traffic and registers.
__global__ __launch_bounds__(256, 2) void attn_p0(
    const ushort* __restrict__ Qb, const ushort* __restrict__ Kb,
    float* __restrict__ lpart)
{
  const int bid = blockIdx.x;
  const int swz = (bid & 7) * 64 + (bid >> 3);   // bijective: 512 % 8 == 0
  const int bh = swz >> 4, stile = (swz >> 1) & 7, half = swz & 1;
  const int s0 = stile * 256;
  const int tid = threadIdx.x, lane = tid & 63, w = tid >> 6;
  const int g = lane >> 4, r15 = lane & 15;

  __shared__ __align__(16) ushort Ks[2][16384];   // dbuf [64 t][256 k], swizzled

  uint4 qr[4][8];
#pragma unroll
  for (int h = 0; h < 4; ++h) {
    const ushort* qrow = &Qb[((size_t)bh * 2048 + s0 + w * 64 + h * 16 + r15) * 256 + g * 8];
#pragma unroll
    for (int kk = 0; kk < 8; kk++) qr[h][kk] = *(const uint4*)&qrow[kk * 32];
  }
#pragma unroll
  for (int h = 0; h < 4; ++h)
#pragma unroll
    for (int kk = 0; kk < 8; kk++)
      asm volatile("" : "+v"(qr[h][kk].x), "+v"(qr[h][kk].y),
                        "+v"(qr[h][kk].z), "+v"(qr[h][kk].w));

  const ushort* Ktile = Kb + ((size_t)bh << 19);
  const int it0 = half * 16, it1 = it0 + 16;

  // prologue: DMA K(it0) -> Ks[0], fence, barrier
#pragma unroll
  for (int i = 0; i < 8; ++i)
    GLD16(&Ktile[(size_t)it0 * 16384 + (i * 256 + tid) * 8], &Ks[0][(i * 256 + tid) * 8]);
  asm volatile("s_waitcnt vmcnt(0)" ::: "memory");
  __syncthreads();

  for (int it = it0; it < it1; ++it) {
    const int cur = it & 1;
    if (it < it1 - 1) {
#pragma unroll
      for (int i = 0; i < 8; ++i)
        GLD16(&Ktile[(size_t)(it + 1) * 16384 + (i * 256 + tid) * 8],
              &Ks[cur ^ 1][(i * 256 + tid) * 8]);
    }

#pragma unroll
    for (int n = 0; n < 4; ++n) {
      f32x4 gh[4];
#pragma unroll
      for (int h = 0; h < 4; ++h) gh[h] = (f32x4){0.f, 0.f, 0.f, 0.f};
#pragma unroll
      for (int kk = 0; kk < 8; ++kk) {
        bf16x8 kb = *(const bf16x8*)&Ks[cur][(n * 16 + r15) * 256 + (((kk * 4 + g) ^ (r15 & 7)) << 3)];
        gh[0] = mfma16(*(const bf16x8*)&qr[0][kk], kb, gh[0]);
        gh[1] = mfma16(*(const bf16x8*)&qr[1][kk], kb, gh[1]);
        gh[2] = mfma16(*(const bf16x8*)&qr[2][kk], kb, gh[2]);
        gh[3] = mfma16(*(const bf16x8*)&qr[3][kk], kb, gh[3]);
      }
      float sn = 0.f;
#pragma unroll
      for (int h = 0; h < 4; ++h)
        sn += fexp2(gh[h][0]) + fexp2(gh[h][1]) + fexp2(gh[h][2]) + fexp2(gh[h][3]);
      sn += __shfl_xor(sn, 16);
      sn += __shfl_xor(sn, 32);
      if (g == 0)
        lpart[((size_t)((stile * 4 + w) * 32 + bh) << 11) + it * 64 + n * 16 + r15] = sn;
    }

    asm volatile("s_waitcnt vmcnt(0)" ::: "memory");
    __syncthreads();
  }
}

// ---------------- attention phase 1: s-tile 128, GLD K staging, one barrier (r23, proven) ----------------
__global__ __launch_bounds__(256, 2) void attn_p1(
    const ushort* __restrict__ Qb, const ushort* __restrict__ Kb,
    const ushort* __restrict__ Vt, ushort* __restrict__ Zb)
{
  const int bid = blockIdx.x;
  const int swz = (bid & 7) * 64 + (bid >> 3);   // bijective: 512 % 8 == 0
  const int bh = swz >> 4, stile = swz & 15;
  const int s0 = stile * 128;
  const int tid = threadIdx.x, lane = tid & 63, w = tid >> 6;
  const int g = lane >> 4, r15 = lane & 15;

  __shared__ __align__(16) ushort Ks[2][8192];
  __shared__ __align__(16) ushort Ps[2][5120];

  bf16x8 q[2][8];
#pragma unroll
  for (int h = 0; h < 2; ++h) {
    const ushort* qrow = &Qb[((size_t)bh * 2048 + s0 + w * 32 + h * 16 + r15) * 256 + g * 8];
#pragma unroll
    for (int kk = 0; kk < 8; kk++) q[h][kk] = *(const bf16x8*)&qrow[kk * 32];
  }

  const ushort* Ktile = Kb + ((size_t)bh << 19);
  const ushort* Vtile = Vt + ((size_t)bh << 19);

  f32x4 acc[8][4];
#pragma unroll
  for (int m = 0; m < 8; m++)
#pragma unroll
    for (int n = 0; n < 4; n++) acc[m][n] = (f32x4){0.f, 0.f, 0.f, 0.f};

  // prologue: DMA K(0) -> Ks[0], fence, barrier
#pragma unroll
  for (int i = 0; i < 4; ++i)
    GLD16(&Ktile[(size_t)(i * 256 + tid) * 8], &Ks[0][(i * 256 + tid) * 8]);
  asm volatile("s_waitcnt vmcnt(0)" ::: "memory");
  __syncthreads();

  for (int it = 0; it < 64; ++it) {
    const int cur = it & 1;
    // ---- top clump: V(it) frags (to regs) + K(it+1) DMA (to LDS) ----
    bf16x8 vb[4];
#pragma unroll
    for (int n = 0; n < 4; ++n)
      vb[n] = *(const bf16x8*)&Vtile[(size_t)it * 8192 + (w * 64 + n * 16 + r15) * 32 + g * 8];
    if (it < 63) {
#pragma unroll
      for (int i = 0; i < 4; ++i)
        GLD16(&Ktile[(size_t)(it + 1) * 8192 + (i * 256 + tid) * 8],
              &Ks[cur ^ 1][(i * 256 + tid) * 8]);
    }

    // ---- QK^T: this wave's 32 s-rows x 32 t from Ks[cur] ----
#pragma unroll
    for (int h = 0; h < 2; ++h) {
      f32x4 gg[2];
      gg[0] = (f32x4){0.f, 0.f, 0.f, 0.f};
      gg[1] = (f32x4){0.f, 0.f, 0.f, 0.f};
#pragma unroll
      for (int n = 0; n < 2; ++n)
#pragma unroll
        for (int kk = 0; kk < 8; ++kk) {
          bf16x8 kb = *(const bf16x8*)&Ks[cur][(n * 16 + r15) * 256 + (((kk * 4 + g) ^ (r15 & 7)) << 3)];
          gg[n] = mfma16(q[h][kk], kb, gg[n]);
        }
#pragma unroll
      for (int n = 0; n < 2; ++n)
#pragma unroll
        for (int rr = 0; rr < 4; ++rr)
          Ps[cur][(w * 32 + h * 16 + g * 4 + rr) * 40 + n * 16 + r15] = f2bf(fexp2(gg[n][rr]));
    }

    // ---- fence: K(it+1) DMA landed (r3-fix) + vb complete; then ONE barrier ----
    asm volatile("s_waitcnt vmcnt(0)" ::: "memory");
    __syncthreads();

    // ---- PV: all 128 s x this wave's 64 e ----
#pragma unroll
    for (int mh = 0; mh < 2; ++mh) {
      bf16x8 pa[4];
#pragma unroll
      for (int m = 0; m < 4; ++m)
        pa[m] = *(const bf16x8*)&Ps[cur][((mh * 4 + m) * 16 + r15) * 40 + g * 8];
#pragma unroll
      for (int n = 0; n < 4; ++n)
#pragma unroll
        for (int m = 0; m < 4; ++m)
          acc[mh * 4 + m][n] = mfma16(pa[m], vb[n], acc[mh * 4 + m][n]);
    }
  }

  const int b = bh >> 3, h = bh & 7;
#pragma unroll
  for (int m = 0; m < 8; m++)
#pragma unroll
    for (int n = 0; n < 4; n++)
#pragma unroll
      for (int rr = 0; rr < 4; rr++) {
        int sl = m * 16 + g * 4 + rr;
        int el = w * 64 + n * 16 + r15;
        Zb[((size_t)(b * 2048 + s0 + sl)) * 2048 + h * 256 + el] = f2bf(acc[m][n][rr]);
      }
}

// ---------------- V' in-place scale by 1/l_t (32 partials) ----------------
__global__ __launch_bounds__(256) void vscale(
    ushort* __restrict__ Vt, const float* __restrict__ lp)
{
  const int tt = blockIdx.x, bh = blockIdx.y, tid = threadIdx.x;
  const int t = tid & 31, pg = tid >> 5;
  __shared__ float red[256];
  __shared__ float cinv[32];
  float s = 0.f;
  for (int p = pg * 4; p < pg * 4 + 4; ++p)
    s += lp[(((size_t)p * 32 + bh) << 11) + tt * 32 + t];
  red[tid] = s;
  __syncthreads();
  if (tid < 32) {
    float tot = 0.f;
#pragma unroll
    for (int i = 0; i < 8; ++i) tot += red[tid + i * 32];
    cinv[tid] = 1.0f / tot;
  }
  __syncthreads();
  size_t base = (((size_t)bh * 64 + tt) << 13) + (size_t)tid * 32;
  ushort buf[32];
#pragma unroll
  for (int i = 0; i < 4; ++i) *(uint4*)&buf[i * 8] = *(const uint4*)&Vt[base + i * 8];
#pragma unroll
  for (int j = 0; j < 32; ++j) buf[j] = f2bf(bf2f(buf[j]) * cinv[j]);
#pragma unroll
  for (int i = 0; i < 4; ++i) *(uint4*)&Vt[base + i * 8] = *(const uint4*)&buf[i * 8];
}

// ---------------- launch ----------------
extern "C" void kernel_launch(void* const* d_in, const int* in_sizes, int n_in,
                              void* d_out, int out_size, void* d_ws, size_t ws_size,
                              hipStream_t stream) {
  const float* x  = (const float*)d_in[0];
  const float* Wq = (const float*)d_in[1];
  const float* bq = (const float*)d_in[2];
  const float* Wk = (const float*)d_in[3];
  const float* bk = (const float*)d_in[4];
  const float* Wv = (const float*)d_in[5];
  const float* bv = (const float*)d_in[6];
  const float* Wo = (const float*)d_in[7];
  const float* bo = (const float*)d_in[8];

  if (ws_size < (size_t)176160768) return; // need 168 MB scratch

  char* ws = (char*)d_ws;
  ushort* bfb = (ushort*)ws;                       // bf16 conversions (8 MB)
  ushort* xb  = bfb;
  ushort* wqb = bfb + 2097152;
  ushort* wkb = bfb + 2621440;
  ushort* wvb = bfb + 3145728;
  ushort* wob = bfb + 3670016;
  ushort* Qb = (ushort*)(ws + 8388608);            // [32,2048,256] (Q pre-scaled log2e/16)
  ushort* Kb = (ushort*)(ws + 41943040);           // [32,2048,256] T2-swizzled
  ushort* Vt = (ushort*)(ws + 75497472);           // [32,64,256,32] tiled V'
  ushort* Zb = (ushort*)(ws + 109051904);          // [8192,2048]
  float*  lp = (float*)(ws + 142606336);           // [32,32,2048] fp32 partial colsums
  float* out = (float*)d_out;

  convert_all<<<4096, 256, 0, stream>>>(x, Wq, Wk, Wv, Wo, bfb);
  gemm_qkv<128, 128><<<dim3(48, 64), 256, 0, stream>>>(
      xb, wqb, wkb, wvb, 256, bq, bk, bv, Qb, Kb, Vt);
  attn_p0<<<512, 256, 0, stream>>>(Qb, Kb, lp);
  vscale<<<dim3(64, 32), 256, 0, stream>>>(Vt, lp);
  attn_p1<<<512, 256, 0, stream>>>(Qb, Kb, Vt, Zb);
  gemm_out<<<dim3(4, 128), 256, 0, stream>>>(Zb, wob, bo, out);
}